// Round 1
// baseline (16163.097 us; speedup 1.0000x reference)
//
#include <hip/hip_runtime.h>

// Problem dims (fixed)
#define Bn 64
#define Tn 512
#define En 1024
#define Hn 1024
#define Vn 50257

typedef __attribute__((ext_vector_type(8))) short short8;
typedef __attribute__((ext_vector_type(4))) float f32x4;

__device__ __forceinline__ unsigned short f2bf(float f) {
    union { float f; unsigned u; } x; x.f = f;
    unsigned r = x.u + 0x7FFFu + ((x.u >> 16) & 1u);   // RNE, values are tame (no NaN/Inf)
    return (unsigned short)(r >> 16);
}
__device__ __forceinline__ float sigm(float x) { return 1.0f / (1.0f + __expf(-x)); }

// Convert fp32 -> bf16 (4 elems/thread)
__global__ __launch_bounds__(256)
void cvt_f32_bf16(const float* __restrict__ src, unsigned short* __restrict__ dst, int n4) {
    int i = blockIdx.x * 256 + threadIdx.x;
    if (i < n4) {
        float4 v = reinterpret_cast<const float4*>(src)[i];
        ushort4 o;
        o.x = f2bf(v.x); o.y = f2bf(v.y); o.z = f2bf(v.z); o.w = f2bf(v.w);
        reinterpret_cast<ushort4*>(dst)[i] = o;
    }
}

// One LSTM timestep. Grid = 64 blocks; block b owns h-cols [16b,16b+16).
// Computes gates[64 rows x 64 cols] where cols = {i,f,g,o} x 16 hcols,
// K = 2048: k<1024 -> emb[tokens[:,t]] @ W_ih^T ; k>=1024 -> h_prev @ W_hh^T.
__global__ __launch_bounds__(256)
void lstm_step(const int* __restrict__ tokens, const float* __restrict__ emb,
               const unsigned short* __restrict__ Wih, const unsigned short* __restrict__ Whh,
               const unsigned short* __restrict__ h_in, unsigned short* __restrict__ h_out,
               float* __restrict__ c_state, int t, int is_last,
               float* __restrict__ out_h, float* __restrict__ out_c)
{
    __shared__ __align__(16) unsigned short Al[64][72];  // +8 pad: 144B stride -> 2-way bank alias (free)
    __shared__ __align__(16) unsigned short Bl[64][72];

    const int tid = threadIdx.x;
    const int hcol0 = blockIdx.x * 16;
    const int w = tid >> 6, l = tid & 63;
    const int lrow = tid >> 2, q = tid & 3;   // loader mapping: 4 threads per row/col

    const int tok = tokens[lrow * Tn + t];
    const float* embrow = emb + (long)tok * En;
    const int gr = (lrow >> 4) * Hn + hcol0 + (lrow & 15);  // gate row for B-col = lrow
    const unsigned short* wihrow = Wih + (long)gr * En;
    const unsigned short* whhrow = Whh + (long)gr * Hn;
    const unsigned short* hrow   = h_in + lrow * Hn;

    f32x4 acc[4];
#pragma unroll
    for (int ct = 0; ct < 4; ++ct) acc[ct] = (f32x4){0.f, 0.f, 0.f, 0.f};

    // MFMA fragment addressing: A row = lane&15, k = 8*(lane>>4)+e (assumed);
    // B col = lane&15, same k. C: col = lane&15, row = (lane>>4)*4 + reg (m89-verified).
    const int arow = w * 16 + (l & 15);
    const int koff = (l >> 4) * 8;

    for (int ch = 0; ch < 32; ++ch) {
        const int k0 = (ch & 15) * 64;
        __syncthreads();
        if (ch < 16) {
            // phase 0: A from embedding (fp32 -> bf16), B from W_ih (bf16)
#pragma unroll
            for (int i2 = 0; i2 < 4; ++i2) {
                const int k = q * 4 + i2 * 16;
                float4 v = *reinterpret_cast<const float4*>(embrow + k0 + k);
                Al[lrow][k + 0] = f2bf(v.x); Al[lrow][k + 1] = f2bf(v.y);
                Al[lrow][k + 2] = f2bf(v.z); Al[lrow][k + 3] = f2bf(v.w);
                *reinterpret_cast<ushort4*>(&Bl[lrow][k]) =
                    *reinterpret_cast<const ushort4*>(wihrow + k0 + k);
            }
        } else {
            // phase 1: A from h_prev (bf16), B from W_hh (bf16)
#pragma unroll
            for (int i2 = 0; i2 < 4; ++i2) {
                const int k = q * 4 + i2 * 16;
                *reinterpret_cast<ushort4*>(&Al[lrow][k]) =
                    *reinterpret_cast<const ushort4*>(hrow + k0 + k);
                *reinterpret_cast<ushort4*>(&Bl[lrow][k]) =
                    *reinterpret_cast<const ushort4*>(whhrow + k0 + k);
            }
        }
        __syncthreads();

        short8 a0 = *reinterpret_cast<const short8*>(&Al[arow][koff]);
        short8 a1 = *reinterpret_cast<const short8*>(&Al[arow][32 + koff]);
#pragma unroll
        for (int ct = 0; ct < 4; ++ct) {
            const int bcol = ct * 16 + (l & 15);
            short8 b0 = *reinterpret_cast<const short8*>(&Bl[bcol][koff]);
            short8 b1 = *reinterpret_cast<const short8*>(&Bl[bcol][32 + koff]);
            acc[ct] = __builtin_amdgcn_mfma_f32_16x16x32_bf16(a0, b0, acc[ct], 0, 0, 0);
            acc[ct] = __builtin_amdgcn_mfma_f32_16x16x32_bf16(a1, b1, acc[ct], 0, 0, 0);
        }
    }

    // LSTM cell update fully in registers: acc[0..3][r] = i,f,g,o at same (row,hcol)
    const int rr0 = w * 16 + (l >> 4) * 4;
    const int hcol = hcol0 + (l & 15);
#pragma unroll
    for (int r = 0; r < 4; ++r) {
        const int row = rr0 + r;
        const int idx = row * Hn + hcol;
        float iv = acc[0][r], fv = acc[1][r], gv = acc[2][r], ov = acc[3][r];
        float c_old = c_state[idx];
        float cn = sigm(fv) * c_old + sigm(iv) * tanhf(gv);
        float hn = sigm(ov) * tanhf(cn);
        c_state[idx] = cn;
        h_out[idx] = f2bf(hn);
        if (is_last) { out_h[idx] = hn; out_c[idx] = cn; }
    }
}

// logits[64, V] = h @ W_cls^T + b_cls. Block n owns vocab cols [64n, 64n+64).
__global__ __launch_bounds__(256)
void classifier(const unsigned short* __restrict__ h,
                const float* __restrict__ Wcls, const float* __restrict__ bcls,
                float* __restrict__ logits)
{
    __shared__ __align__(16) unsigned short Al[64][72];
    __shared__ __align__(16) unsigned short Bl[64][72];

    const int tid = threadIdx.x;
    const int v0 = blockIdx.x * 64;
    const int w = tid >> 6, l = tid & 63;
    const int lrow = tid >> 2, q = tid & 3;
    const int v = v0 + lrow;

    const unsigned short* hrow = h + lrow * Hn;
    const float* wrow = Wcls + (long)v * Hn;

    f32x4 acc[4];
#pragma unroll
    for (int ct = 0; ct < 4; ++ct) acc[ct] = (f32x4){0.f, 0.f, 0.f, 0.f};

    const int arow = w * 16 + (l & 15);
    const int koff = (l >> 4) * 8;

    for (int ch = 0; ch < 16; ++ch) {
        const int k0 = ch * 64;
        __syncthreads();
#pragma unroll
        for (int i2 = 0; i2 < 4; ++i2) {
            const int k = q * 4 + i2 * 16;
            *reinterpret_cast<ushort4*>(&Al[lrow][k]) =
                *reinterpret_cast<const ushort4*>(hrow + k0 + k);
            if (v < Vn) {
                float4 x = *reinterpret_cast<const float4*>(wrow + k0 + k);
                Bl[lrow][k + 0] = f2bf(x.x); Bl[lrow][k + 1] = f2bf(x.y);
                Bl[lrow][k + 2] = f2bf(x.z); Bl[lrow][k + 3] = f2bf(x.w);
            } else {
                ushort4 z; z.x = z.y = z.z = z.w = 0;
                *reinterpret_cast<ushort4*>(&Bl[lrow][k]) = z;
            }
        }
        __syncthreads();

        short8 a0 = *reinterpret_cast<const short8*>(&Al[arow][koff]);
        short8 a1 = *reinterpret_cast<const short8*>(&Al[arow][32 + koff]);
#pragma unroll
        for (int ct = 0; ct < 4; ++ct) {
            const int bcol = ct * 16 + (l & 15);
            short8 b0 = *reinterpret_cast<const short8*>(&Bl[bcol][koff]);
            short8 b1 = *reinterpret_cast<const short8*>(&Bl[bcol][32 + koff]);
            acc[ct] = __builtin_amdgcn_mfma_f32_16x16x32_bf16(a0, b0, acc[ct], 0, 0, 0);
            acc[ct] = __builtin_amdgcn_mfma_f32_16x16x32_bf16(a1, b1, acc[ct], 0, 0, 0);
        }
    }

    const int rr0 = w * 16 + (l >> 4) * 4;
#pragma unroll
    for (int ct = 0; ct < 4; ++ct) {
        const int vv = v0 + ct * 16 + (l & 15);
        if (vv < Vn) {
            float bb = bcls[vv];
#pragma unroll
            for (int r = 0; r < 4; ++r) {
                logits[(long)(rr0 + r) * Vn + vv] = acc[ct][r] + bb;
            }
        }
    }
}

extern "C" void kernel_launch(void* const* d_in, const int* in_sizes, int n_in,
                              void* d_out, int out_size, void* d_ws, size_t ws_size,
                              hipStream_t stream)
{
    const int*   tokens = (const int*)d_in[0];
    const float* W_ih   = (const float*)d_in[2];
    const float* emb    = (const float*)d_in[1];
    const float* W_hh   = (const float*)d_in[3];
    const float* W_cls  = (const float*)d_in[4];
    const float* b_cls  = (const float*)d_in[5];
    float* out = (float*)d_out;

    // ws layout: [hbuf0 128K][hbuf1 128K][c_state 256K][Wih_bf 8M][Whh_bf 8M]  (~17.3 MB)
    char* ws = (char*)d_ws;
    unsigned short* hbuf0 = (unsigned short*)ws;
    unsigned short* hbuf1 = (unsigned short*)(ws + 131072);
    float*          cst   = (float*)(ws + 262144);
    unsigned short* Wih_b = (unsigned short*)(ws + 524288);
    unsigned short* Whh_b = (unsigned short*)(ws + 524288 + 8388608);

    // zero h(t=0) and c(t=0) every call (ws is not re-poisoned between replays)
    hipMemsetAsync(ws, 0, 524288, stream);

    const int n4 = (4 * Hn * En) / 4;  // 1,048,576 float4 groups per weight
    cvt_f32_bf16<<<n4 / 256, 256, 0, stream>>>(W_ih, Wih_b, n4);
    cvt_f32_bf16<<<n4 / 256, 256, 0, stream>>>(W_hh, Whh_b, n4);

    float* out_h = out + (long)Bn * Vn;
    float* out_c = out_h + Bn * Hn;

    for (int t = 0; t < Tn; ++t) {
        const unsigned short* hin = (t & 1) ? hbuf1 : hbuf0;
        unsigned short*       hout = (t & 1) ? hbuf0 : hbuf1;
        lstm_step<<<64, 256, 0, stream>>>(tokens, emb, Wih_b, Whh_b, hin, hout,
                                          cst, t, (t == Tn - 1) ? 1 : 0, out_h, out_c);
    }
    // t=511 (odd) wrote h into hbuf0
    classifier<<<(Vn + 63) / 64, 256, 0, stream>>>(hbuf0, W_cls, b_cls, out);
}

// Round 2
// 10961.635 us; speedup vs baseline: 1.4745x; 1.4745x over previous
//
#include <hip/hip_runtime.h>
#include <hip/hip_cooperative_groups.h>

namespace cg = cooperative_groups;

// Problem dims (fixed)
#define Bn 64
#define Tn 512
#define En 1024
#define Hn 1024
#define Vn 50257
#define CHUNK 64          // timesteps per cooperative launch
#define NCHUNK (Tn / CHUNK)

typedef __attribute__((ext_vector_type(8))) short short8;
typedef __attribute__((ext_vector_type(4))) float f32x4;

__device__ __forceinline__ unsigned short f2bf(float f) {
    union { float f; unsigned u; } x; x.f = f;
    unsigned r = x.u + 0x7FFFu + ((x.u >> 16) & 1u);   // RNE; values are tame
    return (unsigned short)(r >> 16);
}
__device__ __forceinline__ float sigm(float x) { return 1.0f / (1.0f + __expf(-x)); }

// ---------------- fp32 -> bf16 weight convert ----------------
__global__ __launch_bounds__(256)
void cvt_f32_bf16(const float* __restrict__ src, unsigned short* __restrict__ dst, int n4) {
    int i = blockIdx.x * 256 + threadIdx.x;
    if (i < n4) {
        float4 v = reinterpret_cast<const float4*>(src)[i];
        ushort4 o;
        o.x = f2bf(v.x); o.y = f2bf(v.y); o.z = f2bf(v.z); o.w = f2bf(v.w);
        reinterpret_cast<ushort4*>(dst)[i] = o;
    }
}

// ---------------- embedding gather for one 64-step chunk ----------------
// X[r][1024] bf16, r = trel*64 + b, token = tokens[b*512 + t0 + trel]
__global__ __launch_bounds__(256)
void gather_x(const int* __restrict__ tokens, const float* __restrict__ emb,
              unsigned short* __restrict__ X, int t0) {
    const int r = blockIdx.x;
    const int trel = r >> 6, b = r & 63;
    const int tok = tokens[b * Tn + t0 + trel];
    const float* src = emb + (size_t)tok * En;
    const int k = threadIdx.x * 4;
    float4 v = *reinterpret_cast<const float4*>(src + k);
    ushort4 o;
    o.x = f2bf(v.x); o.y = f2bf(v.y); o.z = f2bf(v.z); o.w = f2bf(v.w);
    *reinterpret_cast<ushort4*>(X + (size_t)r * En + k) = o;
}

// ---------------- G = X @ W_ih^T  (4096 x 4096, K=1024) ----------------
// 128x128 tiles, 4 waves each computing a 64x64 quadrant (4x4 MFMA frags).
__global__ __launch_bounds__(256)
void gemm_gin(const unsigned short* __restrict__ X, const unsigned short* __restrict__ Wih,
              float* __restrict__ G) {
    __shared__ __align__(16) unsigned short As[128][72];   // 144B row stride: 2-way bank alias (free)
    __shared__ __align__(16) unsigned short Bs[128][72];

    const int tid = threadIdx.x;
    const int bx = blockIdx.x & 31;   // N tile
    const int by = blockIdx.x >> 5;   // M tile
    const int w = tid >> 6, l = tid & 63;
    const int wr = w >> 1, wc = w & 1;

    f32x4 acc[4][4];
#pragma unroll
    for (int i = 0; i < 4; ++i)
#pragma unroll
        for (int j = 0; j < 4; ++j) acc[i][j] = (f32x4){0.f, 0.f, 0.f, 0.f};

    const int koff = (l >> 4) * 8;

    for (int kk = 0; kk < En / 64; ++kk) {
        __syncthreads();
        // stage A (X rows) and B (W_ih rows) tiles: 128x64 bf16 each
#pragma unroll
        for (int j = 0; j < 4; ++j) {
            const int u = tid * 4 + j;          // 16B unit, 1024 units
            const int row = u >> 3, ku = (u & 7) * 8;
            *reinterpret_cast<short8*>(&As[row][ku]) =
                *reinterpret_cast<const short8*>(X + (size_t)(by * 128 + row) * En + kk * 64 + ku);
            *reinterpret_cast<short8*>(&Bs[row][ku]) =
                *reinterpret_cast<const short8*>(Wih + (size_t)(bx * 128 + row) * En + kk * 64 + ku);
        }
        __syncthreads();

#pragma unroll
        for (int kc = 0; kc < 2; ++kc) {
            const int k0 = kc * 32 + koff;
            short8 af[4], bf[4];
#pragma unroll
            for (int i = 0; i < 4; ++i)
                af[i] = *reinterpret_cast<const short8*>(&As[wr * 64 + i * 16 + (l & 15)][k0]);
#pragma unroll
            for (int j = 0; j < 4; ++j)
                bf[j] = *reinterpret_cast<const short8*>(&Bs[wc * 64 + j * 16 + (l & 15)][k0]);
#pragma unroll
            for (int i = 0; i < 4; ++i)
#pragma unroll
                for (int j = 0; j < 4; ++j)
                    acc[i][j] = __builtin_amdgcn_mfma_f32_16x16x32_bf16(af[i], bf[j], acc[i][j], 0, 0, 0);
        }
    }

    const int rr = 4 * (l >> 4);
#pragma unroll
    for (int i = 0; i < 4; ++i) {
        const int row = by * 128 + wr * 64 + i * 16 + rr;
#pragma unroll
        for (int j = 0; j < 4; ++j) {
            const int col = bx * 128 + wc * 64 + j * 16 + (l & 15);
#pragma unroll
            for (int r = 0; r < 4; ++r)
                G[(size_t)(row + r) * 4096 + col] = acc[i][j][r];
        }
    }
}

// ---------------- persistent recurrent kernel: 64 steps, grid.sync per step --------
// 128 blocks x 256 threads. Block b owns hcols [8b, 8b+8).
// Gate cols (32) as 2 MFMA col-tiles: tile0 = [i|f] x 8 hcols, tile1 = [g|o] x 8 hcols.
// W_hh slice (64 KB) XOR-swizzled in LDS for the whole chunk. c-state in registers.
__global__ __launch_bounds__(256)
void lstm_chunk(const float* __restrict__ G, const unsigned short* __restrict__ Whh,
                unsigned short* __restrict__ h0, unsigned short* __restrict__ h1,
                float* __restrict__ c_state, int t0,
                float* __restrict__ out_h, float* __restrict__ out_c)
{
    __shared__ __align__(16) unsigned short Wl[32 * 1024];   // 64 KB

    const int tid = threadIdx.x;
    const int b = blockIdx.x;
    const int w = tid >> 6, l = tid & 63;

    // ---- stage W_hh slice into swizzled LDS (once per chunk) ----
    // lds byte fb = c*2048 + kb, stored at fb ^ ((c&7)<<4)
#pragma unroll
    for (int j = 0; j < 16; ++j) {
        const int u = tid * 16 + j;            // 16B units, 4096 total
        const int fb = u * 16;
        const int cc = fb >> 11;               // col 0..31
        const int kb = fb & 2047;
        const int gate = (cc >> 4) * 2 + ((cc & 15) >> 3);
        const int hcol = b * 8 + (cc & 7);
        short8 v = *reinterpret_cast<const short8*>(Whh + (size_t)(gate * Hn + hcol) * Hn + kb / 2);
        *reinterpret_cast<short8*>((char*)Wl + (fb ^ ((cc & 7) << 4))) = v;
    }

    const int rowbase = w * 16 + ((l >> 4) << 2);
    const int hcol = b * 8 + (l & 7);
    float c_reg[4];
#pragma unroll
    for (int r = 0; r < 4; ++r) c_reg[r] = c_state[(rowbase + r) * Hn + hcol];

    const int arow = w * 16 + (l & 15);
    const int koff = (l >> 4) * 8;
    const int c0 = (l & 15);           // tile0 LDS col
    const int c1 = 16 + (l & 15);      // tile1 LDS col
    const int sg = (l & 15) >> 3;
    const int gcol0 = sg * Hn + hcol;          // i (sg=0) / f (sg=1)
    const int gcol1 = (2 + sg) * Hn + hcol;    // g / o

    __syncthreads();
    cg::grid_group grid = cg::this_grid();

    for (int s = 0; s < CHUNK; ++s) {
        const int t = t0 + s;
        const unsigned short* hin = (t & 1) ? h1 : h0;
        unsigned short* hout = (t & 1) ? h0 : h1;

        // issue the G_in loads early; consumed only at the cell update
        const float* Gt = G + (size_t)s * Bn * 4096;
        float g0[4], g1[4];
#pragma unroll
        for (int r = 0; r < 4; ++r) {
            g0[r] = Gt[(size_t)(rowbase + r) * 4096 + gcol0];
            g1[r] = Gt[(size_t)(rowbase + r) * 4096 + gcol1];
        }

        f32x4 acc0 = (f32x4){0.f, 0.f, 0.f, 0.f};
        f32x4 acc1 = (f32x4){0.f, 0.f, 0.f, 0.f};

        const unsigned short* arow_p = hin + (size_t)arow * Hn + koff;
#pragma unroll 8
        for (int kc = 0; kc < 32; ++kc) {
            const int k0 = kc * 32;
            short8 a = *reinterpret_cast<const short8*>(arow_p + k0);
            short8 b0 = *reinterpret_cast<const short8*>(
                (char*)Wl + ((c0 * 2048 + (k0 + koff) * 2) ^ ((c0 & 7) << 4)));
            short8 b1 = *reinterpret_cast<const short8*>(
                (char*)Wl + ((c1 * 2048 + (k0 + koff) * 2) ^ ((c1 & 7) << 4)));
            acc0 = __builtin_amdgcn_mfma_f32_16x16x32_bf16(a, b0, acc0, 0, 0, 0);
            acc1 = __builtin_amdgcn_mfma_f32_16x16x32_bf16(a, b1, acc1, 0, 0, 0);
        }

        // cell update: lane l pairs with l^8 to combine {i,f} and {g,o}
#pragma unroll
        for (int r = 0; r < 4; ++r) {
            float v0 = acc0[r] + g0[r];
            float v1 = acc1[r] + g1[r];
            float p0 = __shfl_xor(v0, 8);
            float p1 = __shfl_xor(v1, 8);
            float iv = (l & 8) ? p0 : v0;
            float fv = (l & 8) ? v0 : p0;
            float gv = (l & 8) ? p1 : v1;
            float ov = (l & 8) ? v1 : p1;
            float cn = sigm(fv) * c_reg[r] + sigm(iv) * tanhf(gv);
            float hn = sigm(ov) * tanhf(cn);
            c_reg[r] = cn;
            if (!(l & 8)) {
                hout[(rowbase + r) * Hn + hcol] = f2bf(hn);
                if (t == Tn - 1) {
                    out_h[(rowbase + r) * Hn + hcol] = hn;
                    out_c[(rowbase + r) * Hn + hcol] = cn;
                }
            }
        }
        grid.sync();
    }

    if (!(l & 8)) {
#pragma unroll
        for (int r = 0; r < 4; ++r) c_state[(rowbase + r) * Hn + hcol] = c_reg[r];
    }
}

// ---------------- classifier: logits[64,V] = h @ W_cls^T + b ----------------
__global__ __launch_bounds__(256)
void classifier(const unsigned short* __restrict__ h,
                const float* __restrict__ Wcls, const float* __restrict__ bcls,
                float* __restrict__ logits)
{
    __shared__ __align__(16) unsigned short Al[64][72];
    __shared__ __align__(16) unsigned short Bl[64][72];

    const int tid = threadIdx.x;
    const int v0 = blockIdx.x * 64;
    const int w = tid >> 6, l = tid & 63;
    const int lrow = tid >> 2, q = tid & 3;
    const int v = v0 + lrow;

    const unsigned short* hrow = h + lrow * Hn;
    const float* wrow = Wcls + (size_t)v * Hn;

    f32x4 acc[4];
#pragma unroll
    for (int ct = 0; ct < 4; ++ct) acc[ct] = (f32x4){0.f, 0.f, 0.f, 0.f};

    const int arow = w * 16 + (l & 15);
    const int koff = (l >> 4) * 8;

    for (int ch = 0; ch < 16; ++ch) {
        const int k0 = ch * 64;
        __syncthreads();
#pragma unroll
        for (int i2 = 0; i2 < 4; ++i2) {
            const int k = q * 4 + i2 * 16;
            *reinterpret_cast<ushort4*>(&Al[lrow][k]) =
                *reinterpret_cast<const ushort4*>(hrow + k0 + k);
            if (v < Vn) {
                float4 x = *reinterpret_cast<const float4*>(wrow + k0 + k);
                Bl[lrow][k + 0] = f2bf(x.x); Bl[lrow][k + 1] = f2bf(x.y);
                Bl[lrow][k + 2] = f2bf(x.z); Bl[lrow][k + 3] = f2bf(x.w);
            } else {
                ushort4 z; z.x = z.y = z.z = z.w = 0;
                *reinterpret_cast<ushort4*>(&Bl[lrow][k]) = z;
            }
        }
        __syncthreads();

        short8 a0 = *reinterpret_cast<const short8*>(&Al[arow][koff]);
        short8 a1 = *reinterpret_cast<const short8*>(&Al[arow][32 + koff]);
#pragma unroll
        for (int ct = 0; ct < 4; ++ct) {
            const int bcol = ct * 16 + (l & 15);
            short8 b0 = *reinterpret_cast<const short8*>(&Bl[bcol][koff]);
            short8 b1 = *reinterpret_cast<const short8*>(&Bl[bcol][32 + koff]);
            acc[ct] = __builtin_amdgcn_mfma_f32_16x16x32_bf16(a0, b0, acc[ct], 0, 0, 0);
            acc[ct] = __builtin_amdgcn_mfma_f32_16x16x32_bf16(a1, b1, acc[ct], 0, 0, 0);
        }
    }

    const int rr0 = w * 16 + (l >> 4) * 4;
#pragma unroll
    for (int ct = 0; ct < 4; ++ct) {
        const int vv = v0 + ct * 16 + (l & 15);
        if (vv < Vn) {
            float bb = bcls[vv];
#pragma unroll
            for (int r = 0; r < 4; ++r)
                logits[(size_t)(rr0 + r) * Vn + vv] = acc[ct][r] + bb;
        }
    }
}

extern "C" void kernel_launch(void* const* d_in, const int* in_sizes, int n_in,
                              void* d_out, int out_size, void* d_ws, size_t ws_size,
                              hipStream_t stream)
{
    const int*   tokens = (const int*)d_in[0];
    const float* emb    = (const float*)d_in[1];
    const float* W_ih   = (const float*)d_in[2];
    const float* W_hh   = (const float*)d_in[3];
    const float* W_cls  = (const float*)d_in[4];
    const float* b_cls  = (const float*)d_in[5];
    float* out = (float*)d_out;

    // ws layout (≈88.5 MB):
    // [h0 128K][h1 128K][c 256K][Wih_bf 8M][Whh_bf 8M][X 8M][G 64M]
    char* ws = (char*)d_ws;
    unsigned short* hbuf0 = (unsigned short*)ws;
    unsigned short* hbuf1 = (unsigned short*)(ws + 131072);
    float*          cst   = (float*)(ws + 262144);
    unsigned short* Wih_b = (unsigned short*)(ws + 524288);
    unsigned short* Whh_b = (unsigned short*)(ws + 524288 + 8388608);
    unsigned short* Xb    = (unsigned short*)(ws + 524288 + 2 * 8388608);
    float*          Gb    = (float*)(ws + 524288 + 3 * 8388608);

    hipMemsetAsync(ws, 0, 524288, stream);   // h(0), c(0) = 0

    const int n4 = (4 * Hn * En) / 4;
    cvt_f32_bf16<<<n4 / 256, 256, 0, stream>>>(W_ih, Wih_b, n4);
    cvt_f32_bf16<<<n4 / 256, 256, 0, stream>>>(W_hh, Whh_b, n4);

    float* out_h = out + (size_t)Bn * Vn;
    float* out_c = out_h + Bn * Hn;

    for (int c = 0; c < NCHUNK; ++c) {
        int t0 = c * CHUNK;
        gather_x<<<CHUNK * Bn, 256, 0, stream>>>(tokens, emb, Xb, t0);
        gemm_gin<<<32 * 32, 256, 0, stream>>>(Xb, Wih_b, Gb);

        void* args[] = {(void*)&Gb, (void*)&Whh_b, (void*)&hbuf0, (void*)&hbuf1,
                        (void*)&cst, (void*)&t0, (void*)&out_h, (void*)&out_c};
        hipLaunchCooperativeKernel((void*)lstm_chunk, dim3(128), dim3(256),
                                   args, 0, stream);
    }

    // t=511 (odd) wrote h into hbuf0
    classifier<<<(Vn + 63) / 64, 256, 0, stream>>>(hbuf0, W_cls, b_cls, out);
}

// Round 4
// 7767.957 us; speedup vs baseline: 2.0807x; 1.4111x over previous
//
#include <hip/hip_runtime.h>

// Problem dims (fixed)
#define Bn 64
#define Tn 512
#define En 1024
#define Hn 1024
#define Vn 50257
#define CHUNK 64
#define NCHUNK (Tn / CHUNK)
#define AGENT __HIP_MEMORY_SCOPE_AGENT

typedef __attribute__((ext_vector_type(8))) short short8;
typedef __attribute__((ext_vector_type(4))) float f32x4;
typedef unsigned long long u64;

__device__ __forceinline__ unsigned short f2bf(float f) {
    union { float f; unsigned u; } x; x.f = f;
    unsigned r = x.u + 0x7FFFu + ((x.u >> 16) & 1u);   // RNE; values are tame
    return (unsigned short)(r >> 16);
}
__device__ __forceinline__ float sigm(float x) { return 1.0f / (1.0f + __expf(-x)); }
__device__ __forceinline__ float tanh_fast(float x) {
    float e = __expf(2.0f * x);
    return (e - 1.0f) / (e + 1.0f);
}

// ---------------- fp32 -> bf16 weight convert ----------------
__global__ __launch_bounds__(256)
void cvt_f32_bf16(const float* __restrict__ src, unsigned short* __restrict__ dst, int n4) {
    int i = blockIdx.x * 256 + threadIdx.x;
    if (i < n4) {
        float4 v = reinterpret_cast<const float4*>(src)[i];
        ushort4 o;
        o.x = f2bf(v.x); o.y = f2bf(v.y); o.z = f2bf(v.z); o.w = f2bf(v.w);
        reinterpret_cast<ushort4*>(dst)[i] = o;
    }
}

// ---------------- embedding gather for one 64-step chunk ----------------
__global__ __launch_bounds__(256)
void gather_x(const int* __restrict__ tokens, const float* __restrict__ emb,
              unsigned short* __restrict__ X, int t0) {
    const int r = blockIdx.x;
    const int trel = r >> 6, b = r & 63;
    const int tok = tokens[b * Tn + t0 + trel];
    const float* src = emb + (size_t)tok * En;
    const int k = threadIdx.x * 4;
    float4 v = *reinterpret_cast<const float4*>(src + k);
    ushort4 o;
    o.x = f2bf(v.x); o.y = f2bf(v.y); o.z = f2bf(v.z); o.w = f2bf(v.w);
    *reinterpret_cast<ushort4*>(X + (size_t)r * En + k) = o;
}

// ---------------- G = X @ W_ih^T  (4096 x 4096, K=1024), fp32 out ----------------
__global__ __launch_bounds__(256)
void gemm_gin(const unsigned short* __restrict__ X, const unsigned short* __restrict__ Wih,
              float* __restrict__ G) {
    __shared__ __align__(16) unsigned short As[128][72];
    __shared__ __align__(16) unsigned short Bs[128][72];

    const int tid = threadIdx.x;
    const int bx = blockIdx.x & 31;
    const int by = blockIdx.x >> 5;
    const int w = tid >> 6, l = tid & 63;
    const int wr = w >> 1, wc = w & 1;

    f32x4 acc[4][4];
#pragma unroll
    for (int i = 0; i < 4; ++i)
#pragma unroll
        for (int j = 0; j < 4; ++j) acc[i][j] = (f32x4){0.f, 0.f, 0.f, 0.f};

    const int koff = (l >> 4) * 8;

    for (int kk = 0; kk < En / 64; ++kk) {
        __syncthreads();
#pragma unroll
        for (int j = 0; j < 4; ++j) {
            const int u = tid * 4 + j;
            const int row = u >> 3, ku = (u & 7) * 8;
            *reinterpret_cast<short8*>(&As[row][ku]) =
                *reinterpret_cast<const short8*>(X + (size_t)(by * 128 + row) * En + kk * 64 + ku);
            *reinterpret_cast<short8*>(&Bs[row][ku]) =
                *reinterpret_cast<const short8*>(Wih + (size_t)(bx * 128 + row) * En + kk * 64 + ku);
        }
        __syncthreads();

#pragma unroll
        for (int kc = 0; kc < 2; ++kc) {
            const int k0 = kc * 32 + koff;
            short8 af[4], bf[4];
#pragma unroll
            for (int i = 0; i < 4; ++i)
                af[i] = *reinterpret_cast<const short8*>(&As[wr * 64 + i * 16 + (l & 15)][k0]);
#pragma unroll
            for (int j = 0; j < 4; ++j)
                bf[j] = *reinterpret_cast<const short8*>(&Bs[wc * 64 + j * 16 + (l & 15)][k0]);
#pragma unroll
            for (int i = 0; i < 4; ++i)
#pragma unroll
                for (int j = 0; j < 4; ++j)
                    acc[i][j] = __builtin_amdgcn_mfma_f32_16x16x32_bf16(af[i], bf[j], acc[i][j], 0, 0, 0);
        }
    }

    const int rr = 4 * (l >> 4);
#pragma unroll
    for (int i = 0; i < 4; ++i) {
        const int row = by * 128 + wr * 64 + i * 16 + rr;
#pragma unroll
        for (int j = 0; j < 4; ++j) {
            const int col = bx * 128 + wc * 64 + j * 16 + (l & 15);
#pragma unroll
            for (int r = 0; r < 4; ++r)
                G[(size_t)(row + r) * 4096 + col] = acc[i][j][r];
        }
    }
}

// ---------------- persistent recurrent kernel: 64 steps, plain launch ----------
// 128 blocks x 256 threads (1 block/CU max -> co-resident by capacity).
// Block b owns 32 gate-cols (tile0=[i|f] x 8 hcols, tile1=[g|o] x 8 hcols).
// Wave w = (rh=w>>1, kh=w&1): rows rh*32..+31, K-half kh. W_hh in 128 VGPRs/lane.
// h exchanged via agent-scope relaxed atomics (coherence point = IC).
// Barrier: monotone counter, relaxed RMW arrive + relaxed spin, bounded.
__global__ __launch_bounds__(256)
void lstm_chunk(const float* __restrict__ G, const unsigned short* __restrict__ Whh,
                unsigned short* __restrict__ h0, unsigned short* __restrict__ h1,
                float* __restrict__ c_state, unsigned* __restrict__ bar, int t0,
                float* __restrict__ out_h, float* __restrict__ out_c)
{
    __shared__ __align__(16) float red[2][2][2][64][4];   // [rh][rt][ct][lane][r] 16KB

    const int tid = threadIdx.x;
    const int b = blockIdx.x;
    const int w = tid >> 6, l = tid & 63;
    const int kh = w & 1, rh = w >> 1;
    const int koff = (l >> 4) * 8;
    const int lc = l & 15;
    const int hcol = b * 8 + (l & 7);

    // ---- W_hh fragments -> registers (once per launch) ----
    short8 breg[2][16];
#pragma unroll
    for (int ct = 0; ct < 2; ++ct) {
        const int gate = ct * 2 + (lc >> 3);
        const unsigned short* wrow = Whh + ((size_t)gate * Hn + (b * 8 + (lc & 7))) * Hn;
#pragma unroll
        for (int j = 0; j < 16; ++j)
            breg[ct][j] = *reinterpret_cast<const short8*>(wrow + (kh * 16 + j) * 32 + koff);
    }

    // ---- c-state in registers for the chunk (kh==0 waves own the update) ----
    float c_reg[2][4];
    if (kh == 0) {
#pragma unroll
        for (int rt = 0; rt < 2; ++rt)
#pragma unroll
            for (int r = 0; r < 4; ++r)
                c_reg[rt][r] = c_state[(rh * 32 + rt * 16 + ((l >> 4) << 2) + r) * Hn + hcol];
    }

    const int sg = lc >> 3;
    const int gc0 = sg * Hn + hcol;          // i (sg=0) / f (sg=1)
    const int gc1 = (2 + sg) * Hn + hcol;    // g / o

    for (int s = 0; s < CHUNK; ++s) {
        const int t = t0 + s;
        const unsigned short* hin = (t & 1) ? h1 : h0;
        unsigned short* hout = (t & 1) ? h0 : h1;

        // ---- hoisted G loads: issued before the MFMA loop, consumed after ----
        float g0[2][4], g1[2][4];
        if (kh == 0) {
            const float* Gt = G + (size_t)s * Bn * 4096;
#pragma unroll
            for (int rt = 0; rt < 2; ++rt) {
                const int rowbase = rh * 32 + rt * 16 + ((l >> 4) << 2);
#pragma unroll
                for (int r = 0; r < 4; ++r) {
                    g0[rt][r] = Gt[(size_t)(rowbase + r) * 4096 + gc0];
                    g1[rt][r] = Gt[(size_t)(rowbase + r) * 4096 + gc1];
                }
            }
        }

        f32x4 acc[2][2];
        acc[0][0] = acc[0][1] = acc[1][0] = acc[1][1] = (f32x4){0.f, 0.f, 0.f, 0.f};

#pragma unroll
        for (int rt = 0; rt < 2; ++rt) {
            const unsigned short* ap =
                hin + (size_t)(rh * 32 + rt * 16 + (l & 15)) * Hn + kh * 512 + koff;
#pragma unroll
            for (int j = 0; j < 16; ++j) {
                u64 lo = __hip_atomic_load((const u64*)(ap + j * 32),     __ATOMIC_RELAXED, AGENT);
                u64 hi = __hip_atomic_load((const u64*)(ap + j * 32 + 4), __ATOMIC_RELAXED, AGENT);
                union { u64 q[2]; short8 v; } ua;
                ua.q[0] = lo; ua.q[1] = hi;
                acc[rt][0] = __builtin_amdgcn_mfma_f32_16x16x32_bf16(ua.v, breg[0][j], acc[rt][0], 0, 0, 0);
                acc[rt][1] = __builtin_amdgcn_mfma_f32_16x16x32_bf16(ua.v, breg[1][j], acc[rt][1], 0, 0, 0);
            }
        }

        // ---- K-split reduction via LDS ----
        if (kh == 1) {
#pragma unroll
            for (int rt = 0; rt < 2; ++rt)
#pragma unroll
                for (int ct = 0; ct < 2; ++ct)
                    *reinterpret_cast<f32x4*>(&red[rh][rt][ct][l][0]) = acc[rt][ct];
        }
        __syncthreads();

        if (kh == 0) {
#pragma unroll
            for (int rt = 0; rt < 2; ++rt) {
                const int rowbase = rh * 32 + rt * 16 + ((l >> 4) << 2);
                f32x4 a0 = acc[rt][0] + *reinterpret_cast<f32x4*>(&red[rh][rt][0][l][0]);
                f32x4 a1 = acc[rt][1] + *reinterpret_cast<f32x4*>(&red[rh][rt][1][l][0]);
#pragma unroll
                for (int r = 0; r < 4; ++r) {
                    float v0 = a0[r] + g0[rt][r];
                    float v1 = a1[r] + g1[rt][r];
                    float p0 = __shfl_xor(v0, 8);
                    float p1 = __shfl_xor(v1, 8);
                    float iv = (l & 8) ? p0 : v0;
                    float fv = (l & 8) ? v0 : p0;
                    float gv = (l & 8) ? p1 : v1;
                    float ov = (l & 8) ? v1 : p1;
                    float cn = sigm(fv) * c_reg[rt][r] + sigm(iv) * tanh_fast(gv);
                    float hn = sigm(ov) * tanh_fast(cn);
                    c_reg[rt][r] = cn;
                    unsigned hb = f2bf(hn);
                    unsigned partner = (unsigned)__shfl_xor((int)hb, 1);
                    if (!(l & 8) && !(l & 1)) {
                        unsigned val = (hb & 0xFFFFu) | (partner << 16);
                        __hip_atomic_store(
                            (unsigned*)(hout + (size_t)(rowbase + r) * Hn + hcol),
                            val, __ATOMIC_RELAXED, AGENT);
                    }
                    if (t == Tn - 1 && !(l & 8)) {
                        out_h[(rowbase + r) * Hn + hcol] = hn;
                        out_c[(rowbase + r) * Hn + hcol] = cn;
                    }
                }
            }
        }

        // ---- lightweight global barrier (no cache flush), bounded spin ----
        asm volatile("s_waitcnt vmcnt(0)" ::: "memory");
        __syncthreads();
        if (tid == 0) {
            __hip_atomic_fetch_add(bar, 1u, __ATOMIC_RELAXED, AGENT);
            const unsigned target = 128u * (unsigned)(t + 1);
            int guard = 0;
            while (__hip_atomic_load(bar, __ATOMIC_RELAXED, AGENT) < target &&
                   guard < (1 << 17)) {
                __builtin_amdgcn_s_sleep(2);
                ++guard;
            }
        }
        __syncthreads();
    }

    if (kh == 0 && !(l & 8)) {
#pragma unroll
        for (int rt = 0; rt < 2; ++rt)
#pragma unroll
            for (int r = 0; r < 4; ++r)
                c_state[(rh * 32 + rt * 16 + ((l >> 4) << 2) + r) * Hn + hcol] = c_reg[rt][r];
    }
}

// ---------------- classifier: logits[64,V] = h @ W_cls^T + b ----------------
__global__ __launch_bounds__(256)
void classifier(const unsigned short* __restrict__ h,
                const float* __restrict__ Wcls, const float* __restrict__ bcls,
                float* __restrict__ logits)
{
    __shared__ __align__(16) unsigned short Al[64][72];
    __shared__ __align__(16) unsigned short Bl[64][72];

    const int tid = threadIdx.x;
    const int v0 = blockIdx.x * 64;
    const int w = tid >> 6, l = tid & 63;
    const int lrow = tid >> 2, q = tid & 3;
    const int v = v0 + lrow;

    const unsigned short* hrow = h + lrow * Hn;
    const float* wrow = Wcls + (size_t)v * Hn;

    f32x4 acc[4];
#pragma unroll
    for (int ct = 0; ct < 4; ++ct) acc[ct] = (f32x4){0.f, 0.f, 0.f, 0.f};

    const int arow = w * 16 + (l & 15);
    const int koff = (l >> 4) * 8;

    for (int ch = 0; ch < 16; ++ch) {
        const int k0 = ch * 64;
        __syncthreads();
#pragma unroll
        for (int i2 = 0; i2 < 4; ++i2) {
            const int k = q * 4 + i2 * 16;
            *reinterpret_cast<ushort4*>(&Al[lrow][k]) =
                *reinterpret_cast<const ushort4*>(hrow + k0 + k);
            if (v < Vn) {
                float4 x = *reinterpret_cast<const float4*>(wrow + k0 + k);
                Bl[lrow][k + 0] = f2bf(x.x); Bl[lrow][k + 1] = f2bf(x.y);
                Bl[lrow][k + 2] = f2bf(x.z); Bl[lrow][k + 3] = f2bf(x.w);
            } else {
                ushort4 z; z.x = z.y = z.z = z.w = 0;
                *reinterpret_cast<ushort4*>(&Bl[lrow][k]) = z;
            }
        }
        __syncthreads();

        short8 a0 = *reinterpret_cast<const short8*>(&Al[arow][koff]);
        short8 a1 = *reinterpret_cast<const short8*>(&Al[arow][32 + koff]);
#pragma unroll
        for (int ct = 0; ct < 4; ++ct) {
            const int bcol = ct * 16 + (l & 15);
            short8 b0 = *reinterpret_cast<const short8*>(&Bl[bcol][koff]);
            short8 b1 = *reinterpret_cast<const short8*>(&Bl[bcol][32 + koff]);
            acc[ct] = __builtin_amdgcn_mfma_f32_16x16x32_bf16(a0, b0, acc[ct], 0, 0, 0);
            acc[ct] = __builtin_amdgcn_mfma_f32_16x16x32_bf16(a1, b1, acc[ct], 0, 0, 0);
        }
    }

    const int rr0 = w * 16 + (l >> 4) * 4;
#pragma unroll
    for (int ct = 0; ct < 4; ++ct) {
        const int vv = v0 + ct * 16 + (l & 15);
        if (vv < Vn) {
            float bb = bcls[vv];
#pragma unroll
            for (int r = 0; r < 4; ++r)
                logits[(size_t)(rr0 + r) * Vn + vv] = acc[ct][r] + bb;
        }
    }
}

extern "C" void kernel_launch(void* const* d_in, const int* in_sizes, int n_in,
                              void* d_out, int out_size, void* d_ws, size_t ws_size,
                              hipStream_t stream)
{
    const int*   tokens = (const int*)d_in[0];
    const float* emb    = (const float*)d_in[1];
    const float* W_ih   = (const float*)d_in[2];
    const float* W_hh   = (const float*)d_in[3];
    const float* W_cls  = (const float*)d_in[4];
    const float* b_cls  = (const float*)d_in[5];
    float* out = (float*)d_out;

    // ws layout (~88.5 MB):
    // [h0 128K][h1 128K][c 256K][bar 4K][Wih_bf 8M][Whh_bf 8M][X 8M][G 64M]
    char* ws = (char*)d_ws;
    unsigned short* hbuf0 = (unsigned short*)ws;
    unsigned short* hbuf1 = (unsigned short*)(ws + 131072);
    float*          cst   = (float*)(ws + 262144);
    unsigned*       bar   = (unsigned*)(ws + 524288);
    unsigned short* Wih_b = (unsigned short*)(ws + 528384);
    unsigned short* Whh_b = (unsigned short*)(ws + 528384 + 8388608);
    unsigned short* Xb    = (unsigned short*)(ws + 528384 + 2 * 8388608);
    float*          Gb    = (float*)(ws + 528384 + 3 * 8388608);

    // zero h(0), c(0), barrier counter each call
    hipMemsetAsync(ws, 0, 532480, stream);

    const int n4 = (4 * Hn * En) / 4;
    cvt_f32_bf16<<<n4 / 256, 256, 0, stream>>>(W_ih, Wih_b, n4);
    cvt_f32_bf16<<<n4 / 256, 256, 0, stream>>>(W_hh, Whh_b, n4);

    float* out_h = out + (size_t)Bn * Vn;
    float* out_c = out_h + Bn * Hn;

    for (int c = 0; c < NCHUNK; ++c) {
        int t0 = c * CHUNK;
        gather_x<<<CHUNK * Bn, 256, 0, stream>>>(tokens, emb, Xb, t0);
        gemm_gin<<<32 * 32, 256, 0, stream>>>(Xb, Wih_b, Gb);
        lstm_chunk<<<128, 256, 0, stream>>>(Gb, Whh_b, hbuf0, hbuf1,
                                            cst, bar, t0, out_h, out_c);
    }

    classifier<<<(Vn + 63) / 64, 256, 0, stream>>>(hbuf0, W_cls, b_cls, out);
}

// Round 5
// 6267.978 us; speedup vs baseline: 2.5787x; 1.2393x over previous
//
#include <hip/hip_runtime.h>

// Problem dims (fixed)
#define Bn 64
#define Tn 512
#define En 1024
#define Hn 1024
#define Vn 50257
#define CHUNK 64
#define NCHUNK (Tn / CHUNK)
#define AGENT __HIP_MEMORY_SCOPE_AGENT

typedef __attribute__((ext_vector_type(8))) short short8;
typedef __attribute__((ext_vector_type(4))) float f32x4;
typedef unsigned long long u64;

__device__ __forceinline__ unsigned short f2bf(float f) {
    union { float f; unsigned u; } x; x.f = f;
    unsigned r = x.u + 0x7FFFu + ((x.u >> 16) & 1u);   // RNE; values are tame
    return (unsigned short)(r >> 16);
}
__device__ __forceinline__ float sigm(float x) { return 1.0f / (1.0f + __expf(-x)); }
__device__ __forceinline__ float tanh_fast(float x) {
    float e = __expf(2.0f * x);
    return (e - 1.0f) / (e + 1.0f);
}

// ---------------- fp32 -> bf16 weight convert ----------------
__global__ __launch_bounds__(256)
void cvt_f32_bf16(const float* __restrict__ src, unsigned short* __restrict__ dst, int n4) {
    int i = blockIdx.x * 256 + threadIdx.x;
    if (i < n4) {
        float4 v = reinterpret_cast<const float4*>(src)[i];
        ushort4 o;
        o.x = f2bf(v.x); o.y = f2bf(v.y); o.z = f2bf(v.z); o.w = f2bf(v.w);
        reinterpret_cast<ushort4*>(dst)[i] = o;
    }
}

// ---------------- embedding gather for one 64-step chunk ----------------
__global__ __launch_bounds__(256)
void gather_x(const int* __restrict__ tokens, const float* __restrict__ emb,
              unsigned short* __restrict__ X, int t0) {
    const int r = blockIdx.x;
    const int trel = r >> 6, b = r & 63;
    const int tok = tokens[b * Tn + t0 + trel];
    const float* src = emb + (size_t)tok * En;
    const int k = threadIdx.x * 4;
    float4 v = *reinterpret_cast<const float4*>(src + k);
    ushort4 o;
    o.x = f2bf(v.x); o.y = f2bf(v.y); o.z = f2bf(v.z); o.w = f2bf(v.w);
    *reinterpret_cast<ushort4*>(X + (size_t)r * En + k) = o;
}

// ---------------- G = X @ W_ih^T  (4096 x 4096, K=1024), fp32 out ----------------
__global__ __launch_bounds__(256)
void gemm_gin(const unsigned short* __restrict__ X, const unsigned short* __restrict__ Wih,
              float* __restrict__ G) {
    __shared__ __align__(16) unsigned short As[128][72];
    __shared__ __align__(16) unsigned short Bs[128][72];

    const int tid = threadIdx.x;
    const int bx = blockIdx.x & 31;
    const int by = blockIdx.x >> 5;
    const int w = tid >> 6, l = tid & 63;
    const int wr = w >> 1, wc = w & 1;

    f32x4 acc[4][4];
#pragma unroll
    for (int i = 0; i < 4; ++i)
#pragma unroll
        for (int j = 0; j < 4; ++j) acc[i][j] = (f32x4){0.f, 0.f, 0.f, 0.f};

    const int koff = (l >> 4) * 8;

    for (int kk = 0; kk < En / 64; ++kk) {
        __syncthreads();
#pragma unroll
        for (int j = 0; j < 4; ++j) {
            const int u = tid * 4 + j;
            const int row = u >> 3, ku = (u & 7) * 8;
            *reinterpret_cast<short8*>(&As[row][ku]) =
                *reinterpret_cast<const short8*>(X + (size_t)(by * 128 + row) * En + kk * 64 + ku);
            *reinterpret_cast<short8*>(&Bs[row][ku]) =
                *reinterpret_cast<const short8*>(Wih + (size_t)(bx * 128 + row) * En + kk * 64 + ku);
        }
        __syncthreads();

#pragma unroll
        for (int kc = 0; kc < 2; ++kc) {
            const int k0 = kc * 32 + koff;
            short8 af[4], bf[4];
#pragma unroll
            for (int i = 0; i < 4; ++i)
                af[i] = *reinterpret_cast<const short8*>(&As[wr * 64 + i * 16 + (l & 15)][k0]);
#pragma unroll
            for (int j = 0; j < 4; ++j)
                bf[j] = *reinterpret_cast<const short8*>(&Bs[wc * 64 + j * 16 + (l & 15)][k0]);
#pragma unroll
            for (int i = 0; i < 4; ++i)
#pragma unroll
                for (int j = 0; j < 4; ++j)
                    acc[i][j] = __builtin_amdgcn_mfma_f32_16x16x32_bf16(af[i], bf[j], acc[i][j], 0, 0, 0);
        }
    }

    const int rr = 4 * (l >> 4);
#pragma unroll
    for (int i = 0; i < 4; ++i) {
        const int row = by * 128 + wr * 64 + i * 16 + rr;
#pragma unroll
        for (int j = 0; j < 4; ++j) {
            const int col = bx * 128 + wc * 64 + j * 16 + (l & 15);
#pragma unroll
            for (int r = 0; r < 4; ++r)
                G[(size_t)(row + r) * 4096 + col] = acc[i][j][r];
        }
    }
}

// ---------------- persistent recurrent kernel: 64 steps, plain launch ----------
// 128 blocks x 256 threads (<=1 block/CU -> co-resident by capacity).
// Block b owns 32 gate-cols (tile0=[i|f] x 8 hcols, tile1=[g|o] x 8 hcols).
// Wave w = (rh=w>>1, kh=w&1): rows rh*32..+31, K-half kh. W_hh in 128 VGPRs/lane.
// h exchanged via agent-scope relaxed atomics (coherence point = IC).
// Barrier: per-block flag lines (no RMW contention), all-poll-all.
__global__ __launch_bounds__(256)
void lstm_chunk(const float* __restrict__ G, const unsigned short* __restrict__ Whh,
                unsigned short* __restrict__ h0, unsigned short* __restrict__ h1,
                float* __restrict__ c_state, unsigned* __restrict__ flags, int t0,
                float* __restrict__ out_h, float* __restrict__ out_c)
{
    __shared__ __align__(16) float red[2][2][2][64][4];   // [rh][rt][ct][lane][r] 16KB

    const int tid = threadIdx.x;
    const int b = blockIdx.x;
    const int w = tid >> 6, l = tid & 63;
    const int kh = w & 1, rh = w >> 1;
    const int koff = (l >> 4) * 8;
    const int lc = l & 15;
    const int hcol = b * 8 + (l & 7);

    // ---- W_hh fragments -> registers (once per launch) ----
    short8 breg[2][16];
#pragma unroll
    for (int ct = 0; ct < 2; ++ct) {
        const int gate = ct * 2 + (lc >> 3);
        const unsigned short* wrow = Whh + ((size_t)gate * Hn + (b * 8 + (lc & 7))) * Hn;
#pragma unroll
        for (int j = 0; j < 16; ++j)
            breg[ct][j] = *reinterpret_cast<const short8*>(wrow + (kh * 16 + j) * 32 + koff);
    }

    // ---- c-state in registers for the chunk (kh==0 waves own the update) ----
    float c_reg[2][4];
    if (kh == 0) {
#pragma unroll
        for (int rt = 0; rt < 2; ++rt)
#pragma unroll
            for (int r = 0; r < 4; ++r)
                c_reg[rt][r] = c_state[(rh * 32 + rt * 16 + ((l >> 4) << 2) + r) * Hn + hcol];
    }

    const int sg = lc >> 3;
    const int gc0 = sg * Hn + hcol;          // i (sg=0) / f (sg=1)
    const int gc1 = (2 + sg) * Hn + hcol;    // g / o

    for (int s = 0; s < CHUNK; ++s) {
        const int t = t0 + s;
        const unsigned short* hin = (t & 1) ? h1 : h0;
        unsigned short* hout = (t & 1) ? h0 : h1;

        // ---- hoisted G loads: issued before the MFMA work, consumed at the end ----
        float g0[2][4], g1[2][4];
        if (kh == 0) {
            const float* Gt = G + (size_t)s * Bn * 4096;
#pragma unroll
            for (int rt = 0; rt < 2; ++rt) {
                const int rowbase = rh * 32 + rt * 16 + ((l >> 4) << 2);
#pragma unroll
                for (int r = 0; r < 4; ++r) {
                    g0[rt][r] = Gt[(size_t)(rowbase + r) * 4096 + gc0];
                    g1[rt][r] = Gt[(size_t)(rowbase + r) * 4096 + gc1];
                }
            }
        }

        // ---- preload ALL h fragments first: 64 independent 8B loads (full MLP) ----
        u64 abuf[2][16][2];
#pragma unroll
        for (int rt = 0; rt < 2; ++rt) {
            const unsigned short* ap =
                hin + (size_t)(rh * 32 + rt * 16 + (l & 15)) * Hn + kh * 512 + koff;
#pragma unroll
            for (int j = 0; j < 16; ++j) {
                abuf[rt][j][0] = __hip_atomic_load((const u64*)(ap + j * 32),     __ATOMIC_RELAXED, AGENT);
                abuf[rt][j][1] = __hip_atomic_load((const u64*)(ap + j * 32 + 4), __ATOMIC_RELAXED, AGENT);
            }
        }

        f32x4 acc[2][2];
        acc[0][0] = acc[0][1] = acc[1][0] = acc[1][1] = (f32x4){0.f, 0.f, 0.f, 0.f};

#pragma unroll
        for (int rt = 0; rt < 2; ++rt) {
#pragma unroll
            for (int j = 0; j < 16; ++j) {
                union { u64 q[2]; short8 v; } ua;
                ua.q[0] = abuf[rt][j][0]; ua.q[1] = abuf[rt][j][1];
                acc[rt][0] = __builtin_amdgcn_mfma_f32_16x16x32_bf16(ua.v, breg[0][j], acc[rt][0], 0, 0, 0);
                acc[rt][1] = __builtin_amdgcn_mfma_f32_16x16x32_bf16(ua.v, breg[1][j], acc[rt][1], 0, 0, 0);
            }
        }

        // ---- K-split reduction via LDS ----
        if (kh == 1) {
#pragma unroll
            for (int rt = 0; rt < 2; ++rt)
#pragma unroll
                for (int ct = 0; ct < 2; ++ct)
                    *reinterpret_cast<f32x4*>(&red[rh][rt][ct][l][0]) = acc[rt][ct];
        }
        __syncthreads();

        if (kh == 0) {
#pragma unroll
            for (int rt = 0; rt < 2; ++rt) {
                const int rowbase = rh * 32 + rt * 16 + ((l >> 4) << 2);
                f32x4 a0 = acc[rt][0] + *reinterpret_cast<f32x4*>(&red[rh][rt][0][l][0]);
                f32x4 a1 = acc[rt][1] + *reinterpret_cast<f32x4*>(&red[rh][rt][1][l][0]);
#pragma unroll
                for (int r = 0; r < 4; ++r) {
                    float v0 = a0[r] + g0[rt][r];
                    float v1 = a1[r] + g1[rt][r];
                    float p0 = __shfl_xor(v0, 8);
                    float p1 = __shfl_xor(v1, 8);
                    float iv = (l & 8) ? p0 : v0;
                    float fv = (l & 8) ? v0 : p0;
                    float gv = (l & 8) ? p1 : v1;
                    float ov = (l & 8) ? v1 : p1;
                    float cn = sigm(fv) * c_reg[rt][r] + sigm(iv) * tanh_fast(gv);
                    float hn = sigm(ov) * tanh_fast(cn);
                    c_reg[rt][r] = cn;
                    unsigned hb = f2bf(hn);
                    unsigned partner = (unsigned)__shfl_xor((int)hb, 1);
                    if (!(l & 8) && !(l & 1)) {
                        unsigned val = (hb & 0xFFFFu) | (partner << 16);
                        __hip_atomic_store(
                            (unsigned*)(hout + (size_t)(rowbase + r) * Hn + hcol),
                            val, __ATOMIC_RELAXED, AGENT);
                    }
                    if (t == Tn - 1 && !(l & 8)) {
                        out_h[(rowbase + r) * Hn + hcol] = hn;
                        out_c[(rowbase + r) * Hn + hcol] = cn;
                    }
                }
            }
        }

        // ---- flag-array barrier: arrive = own-line store, wait = poll distinct lines ----
        asm volatile("s_waitcnt vmcnt(0)" ::: "memory");
        __syncthreads();
        if (tid == 0)
            __hip_atomic_store(&flags[b * 32], (unsigned)(t + 1), __ATOMIC_RELAXED, AGENT);
        if (tid < 128) {
            const unsigned target = (unsigned)(t + 1);
            int guard = 0;
            while (__hip_atomic_load(&flags[tid * 32], __ATOMIC_RELAXED, AGENT) < target &&
                   guard < (1 << 16)) {
                __builtin_amdgcn_s_sleep(1);
                ++guard;
            }
        }
        __syncthreads();
    }

    if (kh == 0 && !(l & 8)) {
#pragma unroll
        for (int rt = 0; rt < 2; ++rt)
#pragma unroll
            for (int r = 0; r < 4; ++r)
                c_state[(rh * 32 + rt * 16 + ((l >> 4) << 2) + r) * Hn + hcol] = c_reg[rt][r];
    }
}

// ---------------- classifier: logits[64,V] = h @ W_cls^T + b ----------------
__global__ __launch_bounds__(256)
void classifier(const unsigned short* __restrict__ h,
                const float* __restrict__ Wcls, const float* __restrict__ bcls,
                float* __restrict__ logits)
{
    __shared__ __align__(16) unsigned short Al[64][72];
    __shared__ __align__(16) unsigned short Bl[64][72];

    const int tid = threadIdx.x;
    const int v0 = blockIdx.x * 64;
    const int w = tid >> 6, l = tid & 63;
    const int lrow = tid >> 2, q = tid & 3;
    const int v = v0 + lrow;

    const unsigned short* hrow = h + lrow * Hn;
    const float* wrow = Wcls + (size_t)v * Hn;

    f32x4 acc[4];
#pragma unroll
    for (int ct = 0; ct < 4; ++ct) acc[ct] = (f32x4){0.f, 0.f, 0.f, 0.f};

    const int arow = w * 16 + (l & 15);
    const int koff = (l >> 4) * 8;

    for (int ch = 0; ch < 16; ++ch) {
        const int k0 = ch * 64;
        __syncthreads();
#pragma unroll
        for (int i2 = 0; i2 < 4; ++i2) {
            const int k = q * 4 + i2 * 16;
            *reinterpret_cast<ushort4*>(&Al[lrow][k]) =
                *reinterpret_cast<const ushort4*>(hrow + k0 + k);
            if (v < Vn) {
                float4 x = *reinterpret_cast<const float4*>(wrow + k0 + k);
                Bl[lrow][k + 0] = f2bf(x.x); Bl[lrow][k + 1] = f2bf(x.y);
                Bl[lrow][k + 2] = f2bf(x.z); Bl[lrow][k + 3] = f2bf(x.w);
            } else {
                ushort4 z; z.x = z.y = z.z = z.w = 0;
                *reinterpret_cast<ushort4*>(&Bl[lrow][k]) = z;
            }
        }
        __syncthreads();

        short8 a0 = *reinterpret_cast<const short8*>(&Al[arow][koff]);
        short8 a1 = *reinterpret_cast<const short8*>(&Al[arow][32 + koff]);
#pragma unroll
        for (int ct = 0; ct < 4; ++ct) {
            const int bcol = ct * 16 + (l & 15);
            short8 b0 = *reinterpret_cast<const short8*>(&Bl[bcol][koff]);
            short8 b1 = *reinterpret_cast<const short8*>(&Bl[bcol][32 + koff]);
            acc[ct] = __builtin_amdgcn_mfma_f32_16x16x32_bf16(a0, b0, acc[ct], 0, 0, 0);
            acc[ct] = __builtin_amdgcn_mfma_f32_16x16x32_bf16(a1, b1, acc[ct], 0, 0, 0);
        }
    }

    const int rr0 = w * 16 + (l >> 4) * 4;
#pragma unroll
    for (int ct = 0; ct < 4; ++ct) {
        const int vv = v0 + ct * 16 + (l & 15);
        if (vv < Vn) {
            float bb = bcls[vv];
#pragma unroll
            for (int r = 0; r < 4; ++r)
                logits[(size_t)(rr0 + r) * Vn + vv] = acc[ct][r] + bb;
        }
    }
}

extern "C" void kernel_launch(void* const* d_in, const int* in_sizes, int n_in,
                              void* d_out, int out_size, void* d_ws, size_t ws_size,
                              hipStream_t stream)
{
    const int*   tokens = (const int*)d_in[0];
    const float* emb    = (const float*)d_in[1];
    const float* W_ih   = (const float*)d_in[2];
    const float* W_hh   = (const float*)d_in[3];
    const float* W_cls  = (const float*)d_in[4];
    const float* b_cls  = (const float*)d_in[5];
    float* out = (float*)d_out;

    // ws layout (~88.5 MB):
    // [h0 128K][h1 128K][c 256K][flags 16K][Wih_bf 8M][Whh_bf 8M][X 8M][G 64M]
    char* ws = (char*)d_ws;
    unsigned short* hbuf0 = (unsigned short*)ws;
    unsigned short* hbuf1 = (unsigned short*)(ws + 131072);
    float*          cst   = (float*)(ws + 262144);
    unsigned*       flags = (unsigned*)(ws + 524288);
    unsigned short* Wih_b = (unsigned short*)(ws + 540672);
    unsigned short* Whh_b = (unsigned short*)(ws + 540672 + 8388608);
    unsigned short* Xb    = (unsigned short*)(ws + 540672 + 2 * 8388608);
    float*          Gb    = (float*)(ws + 540672 + 3 * 8388608);

    // zero h(0), c(0), flags each call
    hipMemsetAsync(ws, 0, 540672, stream);

    const int n4 = (4 * Hn * En) / 4;
    cvt_f32_bf16<<<n4 / 256, 256, 0, stream>>>(W_ih, Wih_b, n4);
    cvt_f32_bf16<<<n4 / 256, 256, 0, stream>>>(W_hh, Whh_b, n4);

    float* out_h = out + (size_t)Bn * Vn;
    float* out_c = out_h + Bn * Hn;

    for (int c = 0; c < NCHUNK; ++c) {
        int t0 = c * CHUNK;
        gather_x<<<CHUNK * Bn, 256, 0, stream>>>(tokens, emb, Xb, t0);
        gemm_gin<<<32 * 32, 256, 0, stream>>>(Xb, Wih_b, Gb);
        lstm_chunk<<<128, 256, 0, stream>>>(Gb, Whh_b, hbuf0, hbuf1,
                                            cst, flags, t0, out_h, out_c);
    }

    classifier<<<(Vn + 63) / 64, 256, 0, stream>>>(hbuf0, W_cls, b_cls, out);
}